// Round 1
// baseline (753.862 us; speedup 1.0000x reference)
//
#include <hip/hip_runtime.h>
#include <stdint.h>

// ---------------------------------------------------------------------------
// AdaptiveDiffAttention on MI355X (gfx950)
// B=16384, DIM=2048, SD=1024, H=4, HD=256, LH=256
// Pipeline: f32->bf16 conversions / weight transposes -> lambda-net GEMM ->
//           lam reduce -> 5 projection GEMMs -> attention core -> WO GEMM
// All GEMMs: bf16 MFMA 16x16x32, 128x128 tile, BK=32, 4 waves, global_load_lds.
// ---------------------------------------------------------------------------

#define NTOK   32768     // B*2 token rows
#define BATCH  16384
#define SDIM   1024
#define ATT_SCALE 0.0625f // 256^-0.5

typedef __attribute__((ext_vector_type(8))) short   s16x8;
typedef __attribute__((ext_vector_type(4))) float   f32x4;
typedef __attribute__((ext_vector_type(8))) unsigned short u16x8;
typedef __attribute__((ext_vector_type(4))) unsigned short u16x4;

__device__ __forceinline__ unsigned short f2bf(float f) {
  unsigned u = __float_as_uint(f);
  u += 0x7FFFu + ((u >> 16) & 1u);   // RNE
  return (unsigned short)(u >> 16);
}
__device__ __forceinline__ float bf2f(unsigned short s) {
  return __uint_as_float((unsigned)s << 16);
}

__device__ __forceinline__ void async16(const void* g, void* l) {
  __builtin_amdgcn_global_load_lds((__attribute__((address_space(1))) void*)g,
                                   (__attribute__((address_space(3))) void*)l,
                                   16, 0, 0);
}

// ---------------------------------------------------------------------------
// GEMM: C[M,N] = A[M,K](bf16) @ Bt[N,K]^T(bf16)  + bias
// MODE 0: store bf16      MODE 1: relu, store bf16      MODE 2: +res, store f32
// grid = (M/128, N/128), block = 256
// ---------------------------------------------------------------------------
template<int MODE>
__global__ __launch_bounds__(256, 2)
void gemm_bf16(const unsigned short* __restrict__ A,
               const unsigned short* __restrict__ Bt,
               const float* __restrict__ bias,
               void* __restrict__ Cout,
               const float* __restrict__ res,
               int Kdim, int Ndim)
{
  __shared__ __align__(16) unsigned short lA[128 * 32];
  __shared__ __align__(16) unsigned short lB[128 * 32];
  const int tid  = threadIdx.x;
  const int lane = tid & 63, wid = tid >> 6;
  const int wm = wid >> 1, wn = wid & 1;          // 2x2 wave grid, 64x64 each
  const int bm = blockIdx.x * 128, bn = blockIdx.y * 128;

  f32x4 acc[4][4];
#pragma unroll
  for (int i = 0; i < 4; ++i)
#pragma unroll
    for (int j = 0; j < 4; ++j) acc[i][j] = (f32x4)0.f;

  // staging geometry: thread t loads 16B; chunk0 rows 0..63, chunk1 rows 64..127
  const int ar = tid >> 2;            // 0..63
  const int ac = (tid & 3) * 8;       // col in elements
  const unsigned short* aG0 = A  + (size_t)(bm + ar) * Kdim + ac;
  const unsigned short* aG1 = aG0 + (size_t)64 * Kdim;
  const unsigned short* bG0 = Bt + (size_t)(bn + ar) * Kdim + ac;
  const unsigned short* bG1 = bG0 + (size_t)64 * Kdim;
  unsigned short* aL0 = lA + wid * 512;
  unsigned short* aL1 = lA + 2048 + wid * 512;
  unsigned short* bL0 = lB + wid * 512;
  unsigned short* bL1 = lB + 2048 + wid * 512;

  const unsigned short* aF = lA + (wm * 64 + (lane & 15)) * 32 + (lane >> 4) * 8;
  const unsigned short* bF = lB + (wn * 64 + (lane & 15)) * 32 + (lane >> 4) * 8;

  for (int k0 = 0; k0 < Kdim; k0 += 32) {
    async16(aG0, aL0); async16(aG1, aL1);
    async16(bG0, bL0); async16(bG1, bL1);
    aG0 += 32; aG1 += 32; bG0 += 32; bG1 += 32;
    __syncthreads();                         // drains vmcnt before barrier
    s16x8 af[4], bw[4];
#pragma unroll
    for (int m = 0; m < 4; ++m) af[m] = *(const s16x8*)(aF + m * 512);
#pragma unroll
    for (int n = 0; n < 4; ++n) bw[n] = *(const s16x8*)(bF + n * 512);
#pragma unroll
    for (int m = 0; m < 4; ++m)
#pragma unroll
      for (int n = 0; n < 4; ++n)
        acc[m][n] = __builtin_amdgcn_mfma_f32_16x16x32_bf16(af[m], bw[n], acc[m][n], 0, 0, 0);
    __syncthreads();
  }

  // C/D layout: col = lane&15, row = (lane>>4)*4 + j   [m89/m91 verified]
  const int r0 = bm + wm * 64 + ((lane >> 4) << 2);
  const int c0 = bn + wn * 64 + (lane & 15);
#pragma unroll
  for (int m = 0; m < 4; ++m) {
#pragma unroll
    for (int n = 0; n < 4; ++n) {
      const int col = c0 + n * 16;
      const float bv = bias[col];
#pragma unroll
      for (int j = 0; j < 4; ++j) {
        const int row = r0 + m * 16 + j;
        float v = acc[m][n][j] + bv;
        const size_t idx = (size_t)row * Ndim + col;
        if (MODE == 0)      ((unsigned short*)Cout)[idx] = f2bf(v);
        else if (MODE == 1) ((unsigned short*)Cout)[idx] = f2bf(fmaxf(v, 0.f));
        else                ((float*)Cout)[idx] = v + res[idx];
      }
    }
  }
}

// ---------------------------------------------------------------------------
// lam[row] = sigmoid( relu_h[row,:] . L2w + L2b ) ; one wave per row
// ---------------------------------------------------------------------------
__global__ void lam_kernel(const unsigned short* __restrict__ h,
                           const float* __restrict__ L2w,
                           const float* __restrict__ L2b,
                           float* __restrict__ lam)
{
  const int lane = threadIdx.x & 63, wid = threadIdx.x >> 6;
  const int row = blockIdx.x * 4 + wid;
  const u16x4 hv = *(const u16x4*)(h + (size_t)row * 256 + lane * 4);
  const float4 wv = ((const float4*)L2w)[lane];
  float s = bf2f(hv[0]) * wv.x + bf2f(hv[1]) * wv.y +
            bf2f(hv[2]) * wv.z + bf2f(hv[3]) * wv.w;
#pragma unroll
  for (int m = 32; m >= 1; m >>= 1) s += __shfl_xor(s, m, 64);
  if (lane == 0) lam[row] = 1.f / (1.f + expf(-(s + L2b[0])));
}

// ---------------------------------------------------------------------------
// Attention core: one block per batch, one wave per head.
// qkv = 5 matrices [NTOK,1024] bf16 (Q1,K1,Q2,K2,V), head slice = 256 cols.
// ---------------------------------------------------------------------------
__global__ __launch_bounds__(256)
void attn_kernel(const unsigned short* __restrict__ qkv,
                 const float* __restrict__ lam,
                 unsigned short* __restrict__ aout)
{
  const size_t PS = (size_t)NTOK * 1024;
  const int b = blockIdx.x;
  const int hd = threadIdx.x >> 6;
  const int lane = threadIdx.x & 63;
  const size_t base = (size_t)(b * 2) * 1024 + hd * 256 + lane * 4;

  float q1[2][4], k1[2][4], q2[2][4], k2[2][4], vv[2][4];
#pragma unroll
  for (int t = 0; t < 2; ++t) {
    const size_t o = base + (size_t)t * 1024;
    u16x4 a0 = *(const u16x4*)(qkv + o);
    u16x4 a1 = *(const u16x4*)(qkv + PS + o);
    u16x4 a2 = *(const u16x4*)(qkv + 2 * PS + o);
    u16x4 a3 = *(const u16x4*)(qkv + 3 * PS + o);
    u16x4 a4 = *(const u16x4*)(qkv + 4 * PS + o);
#pragma unroll
    for (int j = 0; j < 4; ++j) {
      q1[t][j] = bf2f(a0[j]); k1[t][j] = bf2f(a1[j]);
      q2[t][j] = bf2f(a2[j]); k2[t][j] = bf2f(a3[j]);
      vv[t][j] = bf2f(a4[j]);
    }
  }

  float d[8];
#pragma unroll
  for (int t = 0; t < 2; ++t)
#pragma unroll
    for (int u = 0; u < 2; ++u) {
      float s1 = 0.f, s2 = 0.f;
#pragma unroll
      for (int j = 0; j < 4; ++j) {
        s1 += q1[t][j] * k1[u][j];
        s2 += q2[t][j] * k2[u][j];
      }
      d[t * 2 + u] = s1;
      d[4 + t * 2 + u] = s2;
    }
#pragma unroll
  for (int i = 0; i < 8; ++i)
#pragma unroll
    for (int m = 32; m >= 1; m >>= 1) d[i] += __shfl_xor(d[i], m, 64);

  const float lm = lam[b];
#pragma unroll
  for (int t = 0; t < 2; ++t) {
    float e0 = d[t * 2 + 0] * ATT_SCALE, e1 = d[t * 2 + 1] * ATT_SCALE;
    float mx = fmaxf(e0, e1);
    float x0 = expf(e0 - mx), x1 = expf(e1 - mx);
    float inv = 1.f / (x0 + x1);
    float a10 = x0 * inv, a11 = x1 * inv;

    float f0 = d[4 + t * 2 + 0] * ATT_SCALE, f1 = d[4 + t * 2 + 1] * ATT_SCALE;
    float mx2 = fmaxf(f0, f1);
    float y0 = expf(f0 - mx2), y1 = expf(f1 - mx2);
    float inv2 = 1.f / (y0 + y1);
    float a20 = y0 * inv2, a21 = y1 * inv2;

    float p0 = fmaxf(a10 - lm * a20, 0.f);
    float p1 = fmaxf(a11 - lm * a21, 0.f);
    u16x4 o;
#pragma unroll
    for (int j = 0; j < 4; ++j) o[j] = f2bf(p0 * vv[0][j] + p1 * vv[1][j]);
    *(u16x4*)(aout + base + (size_t)t * 1024) = o;
  }
}

// ---------------------------------------------------------------------------
// conversions
// ---------------------------------------------------------------------------
__global__ void f32_to_bf16_k(const float* __restrict__ in,
                              unsigned short* __restrict__ out, int n8)
{
  const int i = blockIdx.x * 256 + threadIdx.x;
  if (i >= n8) return;
  const float4* p = (const float4*)in + (size_t)i * 2;
  float4 a = p[0], b = p[1];
  u16x8 v;
  v[0] = f2bf(a.x); v[1] = f2bf(a.y); v[2] = f2bf(a.z); v[3] = f2bf(a.w);
  v[4] = f2bf(b.x); v[5] = f2bf(b.y); v[6] = f2bf(b.z); v[7] = f2bf(b.w);
  *(u16x8*)(out + (size_t)i * 8) = v;
}

// W f32 [K,N] -> Wt bf16 [N,K]; grid (N/32, K/32), block (32,8)
__global__ void transpose_bf16_k(const float* __restrict__ W,
                                 unsigned short* __restrict__ Wt, int K, int N)
{
  __shared__ float tile[32][33];
  const int bn = blockIdx.x * 32, bk = blockIdx.y * 32;
  const int tx = threadIdx.x, ty = threadIdx.y;
#pragma unroll
  for (int i = ty; i < 32; i += 8)
    tile[i][tx] = W[(size_t)(bk + i) * N + bn + tx];
  __syncthreads();
#pragma unroll
  for (int i = ty; i < 32; i += 8)
    Wt[(size_t)(bn + i) * K + bk + tx] = f2bf(tile[tx][i]);
}

// ---------------------------------------------------------------------------
extern "C" void kernel_launch(void* const* d_in, const int* in_sizes, int n_in,
                              void* d_out, int out_size, void* d_ws, size_t ws_size,
                              hipStream_t stream)
{
  const float* x    = (const float*)d_in[0];
  const float* WQ1w = (const float*)d_in[1];  const float* WQ1b = (const float*)d_in[2];
  const float* WK1w = (const float*)d_in[3];  const float* WK1b = (const float*)d_in[4];
  const float* WQ2w = (const float*)d_in[5];  const float* WQ2b = (const float*)d_in[6];
  const float* WK2w = (const float*)d_in[7];  const float* WK2b = (const float*)d_in[8];
  const float* WVw  = (const float*)d_in[9];  const float* WVb  = (const float*)d_in[10];
  const float* WOw  = (const float*)d_in[11]; const float* WOb  = (const float*)d_in[12];
  const float* L1w  = (const float*)d_in[13]; const float* L1b  = (const float*)d_in[14];
  const float* L2w  = (const float*)d_in[15]; const float* L2b  = (const float*)d_in[16];

  char* ws = (char*)d_ws;
  size_t off = 0;
  unsigned short* x_bf = (unsigned short*)(ws + off); off += (size_t)33554432 * 2;  // [32768,1024] / [16384,2048]
  unsigned short* wt[6];
  for (int i = 0; i < 6; ++i) { wt[i] = (unsigned short*)(ws + off); off += (size_t)1048576 * 2; }
  unsigned short* l1t  = (unsigned short*)(ws + off); off += (size_t)524288 * 2;    // [256,2048]
  unsigned short* qkv  = (unsigned short*)(ws + off); off += (size_t)5 * 33554432 * 2;
  unsigned short* abuf = (unsigned short*)(ws + off); off += (size_t)33554432 * 2;
  unsigned short* hbuf = (unsigned short*)(ws + off); off += (size_t)16384 * 256 * 2;
  float*          lam  = (float*)(ws + off);          off += (size_t)16384 * 4;

  // conversions
  f32_to_bf16_k<<<4194304 / 256, 256, 0, stream>>>(x, x_bf, 4194304);
  dim3 tb(32, 8);
  const float* wsrc[6] = {WQ1w, WK1w, WQ2w, WK2w, WVw, WOw};
  for (int i = 0; i < 6; ++i)
    transpose_bf16_k<<<dim3(32, 32), tb, 0, stream>>>(wsrc[i], wt[i], 1024, 1024);
  transpose_bf16_k<<<dim3(8, 64), tb, 0, stream>>>(L1w, l1t, 2048, 256);

  // lambda net: h = relu(x @ L1 + b1)  [16384, 256]
  gemm_bf16<1><<<dim3(128, 2), 256, 0, stream>>>(x_bf, l1t, L1b, hbuf, nullptr, 2048, 256);
  lam_kernel<<<4096, 256, 0, stream>>>(hbuf, L2w, L2b, lam);

  // projections: [32768,1024] @ [1024,1024] for Q1,K1,Q2,K2,V
  const float* pb[5] = {WQ1b, WK1b, WQ2b, WK2b, WVb};
  for (int i = 0; i < 5; ++i)
    gemm_bf16<0><<<dim3(256, 8), 256, 0, stream>>>(
        x_bf, wt[i], pb[i], qkv + (size_t)i * 33554432, nullptr, 1024, 1024);

  // attention core
  attn_kernel<<<16384, 256, 0, stream>>>(qkv, lam, abuf);

  // output: attn @ WO + bias + residual(x), f32
  gemm_bf16<2><<<dim3(256, 8), 256, 0, stream>>>(abuf, wt[5], WOb, d_out, x, 1024, 1024);
}

// Round 2
// 649.747 us; speedup vs baseline: 1.1602x; 1.1602x over previous
//
#include <hip/hip_runtime.h>
#include <stdint.h>

// ---------------------------------------------------------------------------
// AdaptiveDiffAttention on MI355X (gfx950)
// B=16384, DIM=2048, SD=1024, H=4, HD=256, LH=256
// Round 2: fused N=5120 projection GEMM, 256x256xBK32 tile, 8 waves,
// 3-buffer counted-vmcnt pipeline (T3+T4), T2 LDS XOR swizzle, T5 setprio,
// T1 XCD swizzle, LDS-staged coalesced epilogues.
// ---------------------------------------------------------------------------

#define BATCH  16384
#define ATT_SCALE 0.0625f // 256^-0.5

typedef __attribute__((ext_vector_type(8))) short   s16x8;
typedef __attribute__((ext_vector_type(4))) float   f32x4;
typedef __attribute__((ext_vector_type(8))) unsigned short u16x8;
typedef __attribute__((ext_vector_type(4))) unsigned short u16x4;

__device__ __forceinline__ unsigned short f2bf(float f) {
  unsigned u = __float_as_uint(f);
  u += 0x7FFFu + ((u >> 16) & 1u);   // RNE
  return (unsigned short)(u >> 16);
}
__device__ __forceinline__ float bf2f(unsigned short s) {
  return __uint_as_float((unsigned)s << 16);
}

__device__ __forceinline__ void async16(const void* g, void* l) {
  __builtin_amdgcn_global_load_lds((__attribute__((address_space(1))) void*)g,
                                   (__attribute__((address_space(3))) void*)l,
                                   16, 0, 0);
}

// ---------------------------------------------------------------------------
// 256x256 GEMM: C[M,N] = A[M,K](bf16) @ Bt[N,K]^T(bf16) + bias
// MODE 0: store bf16   MODE 2: +res, store f32
// 512 threads = 8 waves (2M x 4N), per-wave 128x64 output, BK=32.
// LDS: 3 buffers x (A 16KB + B 16KB) = 96KB. Chunk-XOR swizzle (T2).
// grid: 1D, NM*NN blocks; n-fast decode after bijective XCD swizzle (T1).
// ---------------------------------------------------------------------------
template<int MODE>
__global__ __launch_bounds__(512, 2)
void gemm256(const unsigned short* __restrict__ A,
             const unsigned short* __restrict__ Bt,
             const float* __restrict__ bias,
             void* __restrict__ Cout,
             const float* __restrict__ res,
             int Kdim, int Ndim, int NN)
{
  __shared__ __align__(16) char lds[98304];
  const int tid  = threadIdx.x;
  const int lane = tid & 63, w = tid >> 6;
  const int wm = w >> 2, wn = w & 3;
  const int li = lane & 15, lc = lane >> 4;

  // T1: bijective XCD swizzle (m204), then n-fast decode
  const int nwg = gridDim.x;
  const int q8 = nwg >> 3, r8 = nwg & 7;
  const int xcd = blockIdx.x & 7, pos = blockIdx.x >> 3;
  const int swz = (xcd < r8 ? xcd * (q8 + 1) : r8 * (q8 + 1) + (xcd - r8) * q8) + pos;
  const int bm = (swz / NN) * 256;
  const int bn = (swz % NN) * 256;

  // staging: per-thread pre-swizzled global offsets (rule #21: linear LDS dest,
  // inverse-swizzled source). Physical chunk P -> logical row r = P>>2,
  // logical k-chunk c = (P&3) ^ ((r>>1)&3).
  size_t aso[2], bso[2];
  int dstA[2], dstB[2];
#pragma unroll
  for (int qq = 0; qq < 2; ++qq) {
    const int P = (qq * 8 + w) * 64 + lane;
    const int r = P >> 2;
    const int c = (P & 3) ^ ((r >> 1) & 3);
    aso[qq] = (size_t)(bm + r) * Kdim + c * 8;
    bso[qq] = (size_t)(bn + r) * Kdim + c * 8;
    dstA[qq] = (qq * 8 + w) * 1024;
    dstB[qq] = 16384 + dstA[qq];
  }

  // fragment LDS byte offsets (same swizzle on the read side)
  const int sxor = (li >> 1) & 3;
  const int afrag = (wm * 128 + li) * 64 + (((lc) ^ sxor) << 4);
  const int bfrag = 16384 + (wn * 64 + li) * 64 + (((lc) ^ sxor) << 4);

  f32x4 acc[8][4];
#pragma unroll
  for (int m = 0; m < 8; ++m)
#pragma unroll
    for (int n = 0; n < 4; ++n) acc[m][n] = (f32x4)0.f;

  const int NT = Kdim >> 5;

  // prologue: stage tiles 0,1; drain tile 0 (4 loads of tile 1 stay in flight)
#pragma unroll
  for (int qq = 0; qq < 2; ++qq) {
    async16(A + aso[qq],      lds + dstA[qq]);
    async16(Bt + bso[qq],     lds + dstB[qq]);
  }
#pragma unroll
  for (int qq = 0; qq < 2; ++qq) {
    async16(A + aso[qq] + 32, lds + 32768 + dstA[qq]);
    async16(Bt + bso[qq] + 32, lds + 32768 + dstB[qq]);
  }
  asm volatile("s_waitcnt vmcnt(4)" ::: "memory");
  __builtin_amdgcn_s_barrier();

  for (int j = 0; j < NT; ++j) {
    const char* cb = lds + (j % 3) * 32768;
    const bool pref = (j + 2 < NT);
    if (pref) {
      char* pb = lds + ((j + 2) % 3) * 32768;
      const int k0 = (j + 2) << 5;
#pragma unroll
      for (int qq = 0; qq < 2; ++qq) {
        async16(A + aso[qq] + k0, pb + dstA[qq]);
        async16(Bt + bso[qq] + k0, pb + dstB[qq]);
      }
    }
    s16x8 bf[4];
#pragma unroll
    for (int n = 0; n < 4; ++n) bf[n] = *(const s16x8*)(cb + bfrag + n * 1024);
#pragma unroll
    for (int mp = 0; mp < 4; ++mp) {
      s16x8 a0 = *(const s16x8*)(cb + afrag + (2 * mp) * 1024);
      s16x8 a1 = *(const s16x8*)(cb + afrag + (2 * mp + 1) * 1024);
      __builtin_amdgcn_s_setprio(1);
#pragma unroll
      for (int n = 0; n < 4; ++n) {
        acc[2 * mp][n]     = __builtin_amdgcn_mfma_f32_16x16x32_bf16(a0, bf[n], acc[2 * mp][n], 0, 0, 0);
        acc[2 * mp + 1][n] = __builtin_amdgcn_mfma_f32_16x16x32_bf16(a1, bf[n], acc[2 * mp + 1][n], 0, 0, 0);
      }
      __builtin_amdgcn_s_setprio(0);
    }
    if (pref) { asm volatile("s_waitcnt vmcnt(4)" ::: "memory"); }
    else      { asm volatile("s_waitcnt vmcnt(0)" ::: "memory"); }
    __builtin_amdgcn_s_barrier();
  }

  // ---- epilogue: per-wave private LDS region (12KB), coalesced stores ----
  float bv[4];
#pragma unroll
  for (int n = 0; n < 4; ++n) bv[n] = bias[bn + wn * 64 + n * 16 + li];

  if (MODE == 0) {
    unsigned short* Cb = (unsigned short*)Cout;
    unsigned short* wl0 = (unsigned short*)(lds + w * 12288);
#pragma unroll
    for (int mp = 0; mp < 4; ++mp) {
      unsigned short* wl = wl0 + (mp & 1) * 2304;
#pragma unroll
      for (int mi = 0; mi < 2; ++mi)
#pragma unroll
        for (int n = 0; n < 4; ++n)
#pragma unroll
          for (int jj = 0; jj < 4; ++jj) {
            float v = acc[mp * 2 + mi][n][jj] + bv[n];
            wl[(mi * 16 + lc * 4 + jj) * 72 + li + n * 16] = f2bf(v);
          }
#pragma unroll
      for (int i = 0; i < 4; ++i) {
        const int rr = i * 8 + (lane >> 3);
        u16x8 vv = *(const u16x8*)(wl + rr * 72 + (lane & 7) * 8);
        const size_t gi = (size_t)(bm + wm * 128 + mp * 32 + rr) * Ndim
                        + bn + wn * 64 + (lane & 7) * 8;
        *(u16x8*)(Cb + gi) = vv;
      }
    }
  } else {
    float* Cf = (float*)Cout;
    float* wl0 = (float*)(lds + w * 12288);
#pragma unroll
    for (int m = 0; m < 8; ++m) {
      float* wl = wl0 + (m & 1) * 1088;
#pragma unroll
      for (int n = 0; n < 4; ++n)
#pragma unroll
        for (int jj = 0; jj < 4; ++jj)
          wl[(lc * 4 + jj) * 68 + li + n * 16] = acc[m][n][jj] + bv[n];
#pragma unroll
      for (int i = 0; i < 4; ++i) {
        const int rr = i * 4 + lc;
        f32x4 vv = *(const f32x4*)(wl + rr * 68 + li * 4);
        const size_t gi = (size_t)(bm + wm * 128 + m * 16 + rr) * Ndim
                        + bn + wn * 64 + li * 4;
        const f32x4 rv = *(const f32x4*)(res + gi);
        *(f32x4*)(Cf + gi) = vv + rv;
      }
    }
  }
}

// ---------------------------------------------------------------------------
// 128x128 GEMM (round-1 structure) — used for the lambda-net hidden GEMM only
// (N=256 gives a 256-block grid here vs 64 with the 256^2 tile).
// MODE 1: relu, store bf16
// ---------------------------------------------------------------------------
__global__ __launch_bounds__(256, 2)
void gemm_bf16_relu(const unsigned short* __restrict__ A,
                    const unsigned short* __restrict__ Bt,
                    const float* __restrict__ bias,
                    unsigned short* __restrict__ Cout,
                    int Kdim, int Ndim)
{
  __shared__ __align__(16) unsigned short lA[128 * 32];
  __shared__ __align__(16) unsigned short lB[128 * 32];
  const int tid  = threadIdx.x;
  const int lane = tid & 63, wid = tid >> 6;
  const int wm = wid >> 1, wn = wid & 1;
  const int bm = blockIdx.x * 128, bn = blockIdx.y * 128;

  f32x4 acc[4][4];
#pragma unroll
  for (int i = 0; i < 4; ++i)
#pragma unroll
    for (int j = 0; j < 4; ++j) acc[i][j] = (f32x4)0.f;

  const int ar = tid >> 2;
  const int ac = (tid & 3) * 8;
  const unsigned short* aG0 = A  + (size_t)(bm + ar) * Kdim + ac;
  const unsigned short* aG1 = aG0 + (size_t)64 * Kdim;
  const unsigned short* bG0 = Bt + (size_t)(bn + ar) * Kdim + ac;
  const unsigned short* bG1 = bG0 + (size_t)64 * Kdim;
  unsigned short* aL0 = lA + wid * 512;
  unsigned short* aL1 = lA + 2048 + wid * 512;
  unsigned short* bL0 = lB + wid * 512;
  unsigned short* bL1 = lB + 2048 + wid * 512;

  const unsigned short* aF = lA + (wm * 64 + (lane & 15)) * 32 + (lane >> 4) * 8;
  const unsigned short* bF = lB + (wn * 64 + (lane & 15)) * 32 + (lane >> 4) * 8;

  for (int k0 = 0; k0 < Kdim; k0 += 32) {
    async16(aG0, aL0); async16(aG1, aL1);
    async16(bG0, bL0); async16(bG1, bL1);
    aG0 += 32; aG1 += 32; bG0 += 32; bG1 += 32;
    __syncthreads();
    s16x8 af[4], bw[4];
#pragma unroll
    for (int m = 0; m < 4; ++m) af[m] = *(const s16x8*)(aF + m * 512);
#pragma unroll
    for (int n = 0; n < 4; ++n) bw[n] = *(const s16x8*)(bF + n * 512);
#pragma unroll
    for (int m = 0; m < 4; ++m)
#pragma unroll
      for (int n = 0; n < 4; ++n)
        acc[m][n] = __builtin_amdgcn_mfma_f32_16x16x32_bf16(af[m], bw[n], acc[m][n], 0, 0, 0);
    __syncthreads();
  }

  const int r0 = bm + wm * 64 + ((lane >> 4) << 2);
  const int c0 = bn + wn * 64 + (lane & 15);
#pragma unroll
  for (int m = 0; m < 4; ++m)
#pragma unroll
    for (int n = 0; n < 4; ++n) {
      const int col = c0 + n * 16;
      const float bvv = bias[col];
#pragma unroll
      for (int j = 0; j < 4; ++j) {
        const int row = r0 + m * 16 + j;
        Cout[(size_t)row * Ndim + col] = f2bf(fmaxf(acc[m][n][j] + bvv, 0.f));
      }
    }
}

// ---------------------------------------------------------------------------
// lam[row] = sigmoid( relu_h[row,:] . L2w + L2b ) ; one wave per row
// ---------------------------------------------------------------------------
__global__ void lam_kernel(const unsigned short* __restrict__ h,
                           const float* __restrict__ L2w,
                           const float* __restrict__ L2b,
                           float* __restrict__ lam)
{
  const int lane = threadIdx.x & 63, wid = threadIdx.x >> 6;
  const int row = blockIdx.x * 4 + wid;
  const u16x4 hv = *(const u16x4*)(h + (size_t)row * 256 + lane * 4);
  const float4 wv = ((const float4*)L2w)[lane];
  float s = bf2f(hv[0]) * wv.x + bf2f(hv[1]) * wv.y +
            bf2f(hv[2]) * wv.z + bf2f(hv[3]) * wv.w;
#pragma unroll
  for (int m = 32; m >= 1; m >>= 1) s += __shfl_xor(s, m, 64);
  if (lane == 0) lam[row] = 1.f / (1.f + expf(-(s + L2b[0])));
}

// ---------------------------------------------------------------------------
// Attention core. qkv = [32768, 5120] bf16 (Q1|K1|Q2|K2|V per row).
// One block per batch, one wave per head; lanes 0-31 -> token 0, 32-63 -> token 1.
// ---------------------------------------------------------------------------
__global__ __launch_bounds__(256)
void attn_kernel(const unsigned short* __restrict__ qkv,
                 const float* __restrict__ lam,
                 unsigned short* __restrict__ aout)
{
  const int b = blockIdx.x;
  const int hd = threadIdx.x >> 6;
  const int lane = threadIdx.x & 63;
  const int g = lane >> 5;          // token index
  const int l5 = lane & 31;
  const size_t base = (size_t)(2 * b + g) * 5120 + hd * 256 + l5 * 8;

  const u16x8 q1v = *(const u16x8*)(qkv + base);
  const u16x8 k1v = *(const u16x8*)(qkv + base + 1024);
  const u16x8 q2v = *(const u16x8*)(qkv + base + 2048);
  const u16x8 k2v = *(const u16x8*)(qkv + base + 3072);
  const u16x8 vvv = *(const u16x8*)(qkv + base + 4096);

  float q1[8], k1[8], q2[8], k2[8], vf[8];
#pragma unroll
  for (int j = 0; j < 8; ++j) {
    q1[j] = bf2f(q1v[j]); k1[j] = bf2f(k1v[j]);
    q2[j] = bf2f(q2v[j]); k2[j] = bf2f(k2v[j]);
    vf[j] = bf2f(vvv[j]);
  }

  float ss1 = 0.f, sc1 = 0.f, ss2 = 0.f, sc2 = 0.f;
#pragma unroll
  for (int j = 0; j < 8; ++j) {
    const float k1o = __shfl_xor(k1[j], 32, 64);
    const float k2o = __shfl_xor(k2[j], 32, 64);
    ss1 += q1[j] * k1[j]; sc1 += q1[j] * k1o;
    ss2 += q2[j] * k2[j]; sc2 += q2[j] * k2o;
  }
#pragma unroll
  for (int m = 16; m >= 1; m >>= 1) {
    ss1 += __shfl_xor(ss1, m, 64); sc1 += __shfl_xor(sc1, m, 64);
    ss2 += __shfl_xor(ss2, m, 64); sc2 += __shfl_xor(sc2, m, 64);
  }

  // group g holds score row q=g: same -> k=g, cross -> k=1-g
  float e0 = ss1 * ATT_SCALE, e1 = sc1 * ATT_SCALE;
  float mx = fmaxf(e0, e1);
  float xs = expf(e0 - mx), xc = expf(e1 - mx);
  float inv = 1.f / (xs + xc);
  const float a1s = xs * inv, a1c = xc * inv;

  e0 = ss2 * ATT_SCALE; e1 = sc2 * ATT_SCALE;
  mx = fmaxf(e0, e1);
  xs = expf(e0 - mx); xc = expf(e1 - mx);
  inv = 1.f / (xs + xc);
  const float a2s = xs * inv, a2c = xc * inv;

  const float lm = lam[b];
  const float ps = fmaxf(a1s - lm * a2s, 0.f);
  const float pc = fmaxf(a1c - lm * a2c, 0.f);

  u16x8 o;
#pragma unroll
  for (int j = 0; j < 8; ++j) {
    const float vo = __shfl_xor(vf[j], 32, 64);
    o[j] = f2bf(ps * vf[j] + pc * vo);
  }
  *(u16x8*)(aout + (size_t)(2 * b + g) * 1024 + hd * 256 + l5 * 8) = o;
}

// ---------------------------------------------------------------------------
// conversions
// ---------------------------------------------------------------------------
__global__ void f32_to_bf16_k(const float* __restrict__ in,
                              unsigned short* __restrict__ out, int n8)
{
  const int i = blockIdx.x * 256 + threadIdx.x;
  if (i >= n8) return;
  const float4* p = (const float4*)in + (size_t)i * 2;
  float4 a = p[0], b = p[1];
  u16x8 v;
  v[0] = f2bf(a.x); v[1] = f2bf(a.y); v[2] = f2bf(a.z); v[3] = f2bf(a.w);
  v[4] = f2bf(b.x); v[5] = f2bf(b.y); v[6] = f2bf(b.z); v[7] = f2bf(b.w);
  *(u16x8*)(out + (size_t)i * 8) = v;
}

// W f32 [K,N] -> Wt bf16 [N,K]; grid (N/32, K/32), block (32,8)
__global__ void transpose_bf16_k(const float* __restrict__ W,
                                 unsigned short* __restrict__ Wt, int K, int N)
{
  __shared__ float tile[32][33];
  const int bn = blockIdx.x * 32, bk = blockIdx.y * 32;
  const int tx = threadIdx.x, ty = threadIdx.y;
#pragma unroll
  for (int i = ty; i < 32; i += 8)
    tile[i][tx] = W[(size_t)(bk + i) * N + bn + tx];
  __syncthreads();
#pragma unroll
  for (int i = ty; i < 32; i += 8)
    Wt[(size_t)(bn + i) * K + bk + tx] = f2bf(tile[tx][i]);
}

__global__ void concat_bias(const float* __restrict__ b0, const float* __restrict__ b1,
                            const float* __restrict__ b2, const float* __restrict__ b3,
                            const float* __restrict__ b4, float* __restrict__ out)
{
  const int i = blockIdx.x * 256 + threadIdx.x;   // 5120 total
  const float* src;
  switch (i >> 10) {
    case 0: src = b0; break;
    case 1: src = b1; break;
    case 2: src = b2; break;
    case 3: src = b3; break;
    default: src = b4; break;
  }
  out[i] = src[i & 1023];
}

// ---------------------------------------------------------------------------
extern "C" void kernel_launch(void* const* d_in, const int* in_sizes, int n_in,
                              void* d_out, int out_size, void* d_ws, size_t ws_size,
                              hipStream_t stream)
{
  const float* x    = (const float*)d_in[0];
  const float* WQ1w = (const float*)d_in[1];  const float* WQ1b = (const float*)d_in[2];
  const float* WK1w = (const float*)d_in[3];  const float* WK1b = (const float*)d_in[4];
  const float* WQ2w = (const float*)d_in[5];  const float* WQ2b = (const float*)d_in[6];
  const float* WK2w = (const float*)d_in[7];  const float* WK2b = (const float*)d_in[8];
  const float* WVw  = (const float*)d_in[9];  const float* WVb  = (const float*)d_in[10];
  const float* WOw  = (const float*)d_in[11]; const float* WOb  = (const float*)d_in[12];
  const float* L1w  = (const float*)d_in[13]; const float* L1b  = (const float*)d_in[14];
  const float* L2w  = (const float*)d_in[15]; const float* L2b  = (const float*)d_in[16];

  char* ws = (char*)d_ws;
  size_t off = 0;
  unsigned short* x_bf = (unsigned short*)(ws + off); off += (size_t)33554432 * 2;   // [32768,1024]
  unsigned short* qw   = (unsigned short*)(ws + off); off += (size_t)5242880 * 2;    // [5120,1024]
  unsigned short* wot  = (unsigned short*)(ws + off); off += (size_t)1048576 * 2;    // [1024,1024]
  unsigned short* l1t  = (unsigned short*)(ws + off); off += (size_t)524288 * 2;     // [256,2048]
  float*          bcat = (float*)(ws + off);          off += (size_t)5120 * 4;
  unsigned short* qkv  = (unsigned short*)(ws + off); off += (size_t)32768 * 5120 * 2; // 320MB
  unsigned short* abuf = (unsigned short*)(ws + off); off += (size_t)33554432 * 2;
  unsigned short* hbuf = (unsigned short*)(ws + off); off += (size_t)16384 * 256 * 2;
  float*          lam  = (float*)(ws + off);          off += (size_t)16384 * 4;

  // conversions
  f32_to_bf16_k<<<4194304 / 256, 256, 0, stream>>>(x, x_bf, 4194304);
  dim3 tb(32, 8);
  const float* wsrc[5] = {WQ1w, WK1w, WQ2w, WK2w, WVw};
  for (int i = 0; i < 5; ++i)
    transpose_bf16_k<<<dim3(32, 32), tb, 0, stream>>>(wsrc[i], qw + (size_t)i * 1048576, 1024, 1024);
  transpose_bf16_k<<<dim3(32, 32), tb, 0, stream>>>(WOw, wot, 1024, 1024);
  transpose_bf16_k<<<dim3(8, 64), tb, 0, stream>>>(L1w, l1t, 2048, 256);
  concat_bias<<<20, 256, 0, stream>>>(WQ1b, WK1b, WQ2b, WK2b, WVb, bcat);

  // lambda net: h = relu(x @ L1 + b1)  [16384, 256]
  gemm_bf16_relu<<<dim3(128, 2), 256, 0, stream>>>(x_bf, l1t, L1b, hbuf, 2048, 256);
  lam_kernel<<<4096, 256, 0, stream>>>(hbuf, L2w, L2b, lam);

  // fused projections: [32768,1024] @ [1024,5120] -> qkv  (Q1|K1|Q2|K2|V)
  gemm256<0><<<dim3(128 * 20), 512, 0, stream>>>(x_bf, qw, bcat, qkv, nullptr, 1024, 5120, 20);

  // attention core
  attn_kernel<<<16384, 256, 0, stream>>>(qkv, lam, abuf);

  // output: attn @ WO + bias + residual(x), f32
  gemm256<2><<<dim3(128 * 4), 512, 0, stream>>>(abuf, wot, WOb, d_out, x, 1024, 1024, 4);
}

// Round 3
// 639.851 us; speedup vs baseline: 1.1782x; 1.0155x over previous
//
#include <hip/hip_runtime.h>
#include <stdint.h>

// ---------------------------------------------------------------------------
// AdaptiveDiffAttention on MI355X (gfx950)
// B=16384, DIM=2048, SD=1024, H=4, HD=256, LH=256
// Round 3: m201-style 8-phase GEMM. BK=64, 2 LDS buffers x {AK0,AK1,BK0,BK1}
// 16KB regions (128KB). 4 phases/tile (ks,mh), per phase: 4-8 ds_read_b128 +
// 1 half-tile global_load_lds prefetch + barrier + 16 MFMA (setprio). Counted
// vmcnt(6) twice per tile (3 half-tiles in flight), tail vmcnt(4)/(0).
// ---------------------------------------------------------------------------

#define BATCH  16384
#define ATT_SCALE 0.0625f // 256^-0.5

typedef __attribute__((ext_vector_type(8))) short   s16x8;
typedef __attribute__((ext_vector_type(4))) float   f32x4;
typedef __attribute__((ext_vector_type(8))) unsigned short u16x8;
typedef __attribute__((ext_vector_type(4))) unsigned short u16x4;

__device__ __forceinline__ unsigned short f2bf(float f) {
  unsigned u = __float_as_uint(f);
  u += 0x7FFFu + ((u >> 16) & 1u);   // RNE
  return (unsigned short)(u >> 16);
}
__device__ __forceinline__ float bf2f(unsigned short s) {
  return __uint_as_float((unsigned)s << 16);
}

__device__ __forceinline__ void async16(const void* g, void* l) {
  __builtin_amdgcn_global_load_lds((__attribute__((address_space(1))) void*)g,
                                   (__attribute__((address_space(3))) void*)l,
                                   16, 0, 0);
}

#define MFMA16(ACCBASE)                                                        \
  __builtin_amdgcn_s_setprio(1);                                               \
  _Pragma("unroll")                                                            \
  for (int mf = 0; mf < 4; ++mf) {                                             \
    _Pragma("unroll")                                                          \
    for (int nf = 0; nf < 4; ++nf)                                             \
      acc[(ACCBASE) + mf][nf] = __builtin_amdgcn_mfma_f32_16x16x32_bf16(       \
          aR[mf], bR[nf], acc[(ACCBASE) + mf][nf], 0, 0, 0);                   \
  }                                                                            \
  __builtin_amdgcn_s_setprio(0);

// ---------------------------------------------------------------------------
// 256x256 GEMM: C[M,N] = A[M,K](bf16) @ Bt[N,K]^T(bf16) + bias
// MODE 0: store bf16   MODE 2: +res, store f32
// 512 threads = 8 waves (2M x 4N), per-wave 128x64 output, BK=64.
// ---------------------------------------------------------------------------
template<int MODE>
__global__ __launch_bounds__(512, 2)
void gemm256(const unsigned short* __restrict__ A,
             const unsigned short* __restrict__ Bt,
             const float* __restrict__ bias,
             void* __restrict__ Cout,
             const float* __restrict__ res,
             int Kdim, int Ndim, int NN)
{
  __shared__ __align__(16) char lds[131072];
  const int tid  = threadIdx.x;
  const int lane = tid & 63, w = tid >> 6;
  const int wm = w >> 2, wn = w & 3;
  const int li = lane & 15, lc = lane >> 4;

  // T1: bijective XCD swizzle (m204), n-fast decode
  const int nwg = gridDim.x;
  const int q8 = nwg >> 3, r8 = nwg & 7;
  const int xcd = blockIdx.x & 7, pos = blockIdx.x >> 3;
  const int swz = (xcd < r8 ? xcd * (q8 + 1) : r8 * (q8 + 1) + (xcd - r8) * q8) + pos;
  const int bm = (swz / NN) * 256;
  const int bn = (swz % NN) * 256;

  // Staging geometry: half-tile = 16KB = [256 rows][32 elems] region; thread
  // does 2x16B. Chunk-XOR swizzle c^=(r>>1)&3 (bank-covering, rule #21:
  // linear LDS dest + inverse-swizzled global source).
  const int r0  = w * 32 + (lane >> 2);      // rows r0, r0+16
  const int csw = ((lane & 3) ^ ((r0 >> 1) & 3)) * 8;  // same for r0+16
  const size_t aS0 = (size_t)(bm + r0) * Kdim + csw;
  const size_t aS1 = (size_t)(bm + r0 + 16) * Kdim + csw;
  const size_t bS0 = (size_t)(bn + r0) * Kdim + csw;
  const size_t bS1 = (size_t)(bn + r0 + 16) * Kdim + csw;
  const int dL0 = w * 2048, dL1 = dL0 + 1024;

  // fragment read offsets (same swizzle on read side)
  const int fsw   = (lc ^ ((li >> 1) & 3)) << 4;
  const int afoff = (wm * 128 + li) * 64 + fsw;
  const int bfoff = 32768 + (wn * 64 + li) * 64 + fsw;

  f32x4 acc[8][4];
#pragma unroll
  for (int m = 0; m < 8; ++m)
#pragma unroll
    for (int n = 0; n < 4; ++n) acc[m][n] = (f32x4)0.f;

  const int NT = Kdim >> 6;

  // prologue: AK0(0) BK0(0) AK1(0) BK1(0) AK0(1) BK0(1)  (issue order matters)
  async16(A  + aS0,       lds + dL0);          async16(A  + aS1,       lds + dL1);
  async16(Bt + bS0,       lds + 32768 + dL0);  async16(Bt + bS1,       lds + 32768 + dL1);
  async16(A  + aS0 + 32,  lds + 16384 + dL0);  async16(A  + aS1 + 32,  lds + 16384 + dL1);
  async16(Bt + bS0 + 32,  lds + 49152 + dL0);  async16(Bt + bS1 + 32,  lds + 49152 + dL1);
  async16(A  + aS0 + 64,  lds + 65536 + dL0);  async16(A  + aS1 + 64,  lds + 65536 + dL1);
  async16(Bt + bS0 + 64,  lds + 98304 + dL0);  async16(Bt + bS1 + 64,  lds + 98304 + dL1);
  asm volatile("s_waitcnt vmcnt(8)" ::: "memory");
  asm volatile("s_barrier" ::: "memory");

  for (int t = 0; t < NT; ++t) {
    char* buf  = lds + (t & 1) * 65536;
    char* nbuf = lds + ((t + 1) & 1) * 65536;
    const size_t kA = (size_t)t * 64;
    s16x8 bR[4];
    // ---- phase 0: ks0 mh0 ; stage AK1(t+1)
    {
      s16x8 aR[4];
      const char* ab = buf + afoff;
      const char* bb = buf + bfoff;
#pragma unroll
      for (int mf = 0; mf < 4; ++mf) aR[mf] = *(const s16x8*)(ab + mf * 1024);
#pragma unroll
      for (int nf = 0; nf < 4; ++nf) bR[nf] = *(const s16x8*)(bb + nf * 1024);
      if (t + 1 < NT) {
        async16(A + aS0 + kA + 96, nbuf + 16384 + dL0);
        async16(A + aS1 + kA + 96, nbuf + 16384 + dL1);
      }
      __builtin_amdgcn_s_barrier();
      MFMA16(0)
      asm volatile("s_barrier" ::: "memory");
    }
    // ---- phase 1: ks0 mh1 ; stage BK1(t+1) ; wait
    {
      s16x8 aR[4];
      const char* ab = buf + afoff + 4096;
#pragma unroll
      for (int mf = 0; mf < 4; ++mf) aR[mf] = *(const s16x8*)(ab + mf * 1024);
      if (t + 1 < NT) {
        async16(Bt + bS0 + kA + 96, nbuf + 49152 + dL0);
        async16(Bt + bS1 + kA + 96, nbuf + 49152 + dL1);
      }
      __builtin_amdgcn_s_barrier();
      MFMA16(4)
      if (t < NT - 1) { asm volatile("s_waitcnt vmcnt(6)" ::: "memory"); }
      else            { asm volatile("s_waitcnt vmcnt(0)" ::: "memory"); }
      asm volatile("s_barrier" ::: "memory");
    }
    // ---- phase 2: ks1 mh0 ; stage AK0(t+2) (same-parity buffer, K0 regions
    //      whose tile-t reads all retired before the end-ph1 barrier)
    {
      s16x8 aR[4];
      const char* ab = buf + 16384 + afoff;
      const char* bb = buf + 16384 + bfoff;
#pragma unroll
      for (int mf = 0; mf < 4; ++mf) aR[mf] = *(const s16x8*)(ab + mf * 1024);
#pragma unroll
      for (int nf = 0; nf < 4; ++nf) bR[nf] = *(const s16x8*)(bb + nf * 1024);
      if (t + 2 < NT) {
        async16(A + aS0 + kA + 128, buf + dL0);
        async16(A + aS1 + kA + 128, buf + dL1);
      }
      __builtin_amdgcn_s_barrier();
      MFMA16(0)
      asm volatile("s_barrier" ::: "memory");
    }
    // ---- phase 3: ks1 mh1 ; stage BK0(t+2) ; wait
    {
      s16x8 aR[4];
      const char* ab = buf + 16384 + afoff + 4096;
#pragma unroll
      for (int mf = 0; mf < 4; ++mf) aR[mf] = *(const s16x8*)(ab + mf * 1024);
      if (t + 2 < NT) {
        async16(Bt + bS0 + kA + 128, buf + 32768 + dL0);
        async16(Bt + bS1 + kA + 128, buf + 32768 + dL1);
      }
      __builtin_amdgcn_s_barrier();
      MFMA16(4)
      if (t < NT - 2)       { asm volatile("s_waitcnt vmcnt(6)" ::: "memory"); }
      else if (t == NT - 2) { asm volatile("s_waitcnt vmcnt(4)" ::: "memory"); }
      else                  { asm volatile("s_waitcnt vmcnt(0)" ::: "memory"); }
      asm volatile("s_barrier" ::: "memory");
    }
  }

  // ---- epilogue: per-wave private LDS region (12KB), coalesced stores ----
  float bv[4];
#pragma unroll
  for (int n = 0; n < 4; ++n) bv[n] = bias[bn + wn * 64 + n * 16 + li];

  if (MODE == 0) {
    unsigned short* Cb = (unsigned short*)Cout;
    unsigned short* wl0 = (unsigned short*)(lds + w * 12288);
#pragma unroll
    for (int mp = 0; mp < 4; ++mp) {
      unsigned short* wl = wl0 + (mp & 1) * 2304;
#pragma unroll
      for (int mi = 0; mi < 2; ++mi)
#pragma unroll
        for (int n = 0; n < 4; ++n)
#pragma unroll
          for (int jj = 0; jj < 4; ++jj) {
            float v = acc[mp * 2 + mi][n][jj] + bv[n];
            wl[(mi * 16 + lc * 4 + jj) * 72 + li + n * 16] = f2bf(v);
          }
#pragma unroll
      for (int i = 0; i < 4; ++i) {
        const int rr = i * 8 + (lane >> 3);
        u16x8 vv = *(const u16x8*)(wl + rr * 72 + (lane & 7) * 8);
        const size_t gi = (size_t)(bm + wm * 128 + mp * 32 + rr) * Ndim
                        + bn + wn * 64 + (lane & 7) * 8;
        *(u16x8*)(Cb + gi) = vv;
      }
    }
  } else {
    float* Cf = (float*)Cout;
    float* wl0 = (float*)(lds + w * 12288);
#pragma unroll
    for (int m = 0; m < 8; ++m) {
      float* wl = wl0 + (m & 1) * 1088;
#pragma unroll
      for (int n = 0; n < 4; ++n)
#pragma unroll
        for (int jj = 0; jj < 4; ++jj)
          wl[(lc * 4 + jj) * 68 + li + n * 16] = acc[m][n][jj] + bv[n];
#pragma unroll
      for (int i = 0; i < 4; ++i) {
        const int rr = i * 4 + lc;
        f32x4 vv = *(const f32x4*)(wl + rr * 68 + li * 4);
        const size_t gi = (size_t)(bm + wm * 128 + m * 16 + rr) * Ndim
                        + bn + wn * 64 + li * 4;
        const f32x4 rv = *(const f32x4*)(res + gi);
        *(f32x4*)(Cf + gi) = vv + rv;
      }
    }
  }
}

// ---------------------------------------------------------------------------
// 128x128 GEMM (round-1 structure) — lambda-net hidden GEMM only.
// ---------------------------------------------------------------------------
__global__ __launch_bounds__(256, 2)
void gemm_bf16_relu(const unsigned short* __restrict__ A,
                    const unsigned short* __restrict__ Bt,
                    const float* __restrict__ bias,
                    unsigned short* __restrict__ Cout,
                    int Kdim, int Ndim)
{
  __shared__ __align__(16) unsigned short lA[128 * 32];
  __shared__ __align__(16) unsigned short lB[128 * 32];
  const int tid  = threadIdx.x;
  const int lane = tid & 63, wid = tid >> 6;
  const int wm = wid >> 1, wn = wid & 1;
  const int bm = blockIdx.x * 128, bn = blockIdx.y * 128;

  f32x4 acc[4][4];
#pragma unroll
  for (int i = 0; i < 4; ++i)
#pragma unroll
    for (int j = 0; j < 4; ++j) acc[i][j] = (f32x4)0.f;

  const int ar = tid >> 2;
  const int ac = (tid & 3) * 8;
  const unsigned short* aG0 = A  + (size_t)(bm + ar) * Kdim + ac;
  const unsigned short* aG1 = aG0 + (size_t)64 * Kdim;
  const unsigned short* bG0 = Bt + (size_t)(bn + ar) * Kdim + ac;
  const unsigned short* bG1 = bG0 + (size_t)64 * Kdim;
  unsigned short* aL0 = lA + wid * 512;
  unsigned short* aL1 = lA + 2048 + wid * 512;
  unsigned short* bL0 = lB + wid * 512;
  unsigned short* bL1 = lB + 2048 + wid * 512;

  const unsigned short* aF = lA + (wm * 64 + (lane & 15)) * 32 + (lane >> 4) * 8;
  const unsigned short* bF = lB + (wn * 64 + (lane & 15)) * 32 + (lane >> 4) * 8;

  for (int k0 = 0; k0 < Kdim; k0 += 32) {
    async16(aG0, aL0); async16(aG1, aL1);
    async16(bG0, bL0); async16(bG1, bL1);
    aG0 += 32; aG1 += 32; bG0 += 32; bG1 += 32;
    __syncthreads();
    s16x8 af[4], bw[4];
#pragma unroll
    for (int m = 0; m < 4; ++m) af[m] = *(const s16x8*)(aF + m * 512);
#pragma unroll
    for (int n = 0; n < 4; ++n) bw[n] = *(const s16x8*)(bF + n * 512);
#pragma unroll
    for (int m = 0; m < 4; ++m)
#pragma unroll
      for (int n = 0; n < 4; ++n)
        acc[m][n] = __builtin_amdgcn_mfma_f32_16x16x32_bf16(af[m], bw[n], acc[m][n], 0, 0, 0);
    __syncthreads();
  }

  const int r0 = bm + wm * 64 + ((lane >> 4) << 2);
  const int c0 = bn + wn * 64 + (lane & 15);
#pragma unroll
  for (int m = 0; m < 4; ++m)
#pragma unroll
    for (int n = 0; n < 4; ++n) {
      const int col = c0 + n * 16;
      const float bvv = bias[col];
#pragma unroll
      for (int j = 0; j < 4; ++j) {
        const int row = r0 + m * 16 + j;
        Cout[(size_t)row * Ndim + col] = f2bf(fmaxf(acc[m][n][j] + bvv, 0.f));
      }
    }
}

// ---------------------------------------------------------------------------
// lam[row] = sigmoid( relu_h[row,:] . L2w + L2b ) ; one wave per row
// ---------------------------------------------------------------------------
__global__ void lam_kernel(const unsigned short* __restrict__ h,
                           const float* __restrict__ L2w,
                           const float* __restrict__ L2b,
                           float* __restrict__ lam)
{
  const int lane = threadIdx.x & 63, wid = threadIdx.x >> 6;
  const int row = blockIdx.x * 4 + wid;
  const u16x4 hv = *(const u16x4*)(h + (size_t)row * 256 + lane * 4);
  const float4 wv = ((const float4*)L2w)[lane];
  float s = bf2f(hv[0]) * wv.x + bf2f(hv[1]) * wv.y +
            bf2f(hv[2]) * wv.z + bf2f(hv[3]) * wv.w;
#pragma unroll
  for (int m = 32; m >= 1; m >>= 1) s += __shfl_xor(s, m, 64);
  if (lane == 0) lam[row] = 1.f / (1.f + expf(-(s + L2b[0])));
}

// ---------------------------------------------------------------------------
// Attention core. qkv = [32768, 5120] bf16 (Q1|K1|Q2|K2|V per row).
// One block per batch, one wave per head; lanes 0-31 token 0, 32-63 token 1.
// ---------------------------------------------------------------------------
__global__ __launch_bounds__(256)
void attn_kernel(const unsigned short* __restrict__ qkv,
                 const float* __restrict__ lam,
                 unsigned short* __restrict__ aout)
{
  const int b = blockIdx.x;
  const int hd = threadIdx.x >> 6;
  const int lane = threadIdx.x & 63;
  const int g = lane >> 5;          // token index
  const int l5 = lane & 31;
  const size_t base = (size_t)(2 * b + g) * 5120 + hd * 256 + l5 * 8;

  const u16x8 q1v = *(const u16x8*)(qkv + base);
  const u16x8 k1v = *(const u16x8*)(qkv + base + 1024);
  const u16x8 q2v = *(const u16x8*)(qkv + base + 2048);
  const u16x8 k2v = *(const u16x8*)(qkv + base + 3072);
  const u16x8 vvv = *(const u16x8*)(qkv + base + 4096);

  float q1[8], k1[8], q2[8], k2[8], vf[8];
#pragma unroll
  for (int j = 0; j < 8; ++j) {
    q1[j] = bf2f(q1v[j]); k1[j] = bf2f(k1v[j]);
    q2[j] = bf2f(q2v[j]); k2[j] = bf2f(k2v[j]);
    vf[j] = bf2f(vvv[j]);
  }

  float ss1 = 0.f, sc1 = 0.f, ss2 = 0.f, sc2 = 0.f;
#pragma unroll
  for (int j = 0; j < 8; ++j) {
    const float k1o = __shfl_xor(k1[j], 32, 64);
    const float k2o = __shfl_xor(k2[j], 32, 64);
    ss1 += q1[j] * k1[j]; sc1 += q1[j] * k1o;
    ss2 += q2[j] * k2[j]; sc2 += q2[j] * k2o;
  }
#pragma unroll
  for (int m = 16; m >= 1; m >>= 1) {
    ss1 += __shfl_xor(ss1, m, 64); sc1 += __shfl_xor(sc1, m, 64);
    ss2 += __shfl_xor(ss2, m, 64); sc2 += __shfl_xor(sc2, m, 64);
  }

  float e0 = ss1 * ATT_SCALE, e1 = sc1 * ATT_SCALE;
  float mx = fmaxf(e0, e1);
  float xs = expf(e0 - mx), xc = expf(e1 - mx);
  float inv = 1.f / (xs + xc);
  const float a1s = xs * inv, a1c = xc * inv;

  e0 = ss2 * ATT_SCALE; e1 = sc2 * ATT_SCALE;
  mx = fmaxf(e0, e1);
  xs = expf(e0 - mx); xc = expf(e1 - mx);
  inv = 1.f / (xs + xc);
  const float a2s = xs * inv, a2c = xc * inv;

  const float lm = lam[b];
  const float ps = fmaxf(a1s - lm * a2s, 0.f);
  const float pc = fmaxf(a1c - lm * a2c, 0.f);

  u16x8 o;
#pragma unroll
  for (int j = 0; j < 8; ++j) {
    const float vo = __shfl_xor(vf[j], 32, 64);
    o[j] = f2bf(ps * vf[j] + pc * vo);
  }
  *(u16x8*)(aout + (size_t)(2 * b + g) * 1024 + hd * 256 + l5 * 8) = o;
}

// ---------------------------------------------------------------------------
// conversions
// ---------------------------------------------------------------------------
__global__ void f32_to_bf16_k(const float* __restrict__ in,
                              unsigned short* __restrict__ out, int n8)
{
  const int i = blockIdx.x * 256 + threadIdx.x;
  if (i >= n8) return;
  const float4* p = (const float4*)in + (size_t)i * 2;
  float4 a = p[0], b = p[1];
  u16x8 v;
  v[0] = f2bf(a.x); v[1] = f2bf(a.y); v[2] = f2bf(a.z); v[3] = f2bf(a.w);
  v[4] = f2bf(b.x); v[5] = f2bf(b.y); v[6] = f2bf(b.z); v[7] = f2bf(b.w);
  *(u16x8*)(out + (size_t)i * 8) = v;
}

// W f32 [K,N] -> Wt bf16 [N,K]; grid (N/32, K/32), block (32,8)
__global__ void transpose_bf16_k(const float* __restrict__ W,
                                 unsigned short* __restrict__ Wt, int K, int N)
{
  __shared__ float tile[32][33];
  const int bn = blockIdx.x * 32, bk = blockIdx.y * 32;
  const int tx = threadIdx.x, ty = threadIdx.y;
#pragma unroll
  for (int i = ty; i < 32; i += 8)
    tile[i][tx] = W[(size_t)(bk + i) * N + bn + tx];
  __syncthreads();
#pragma unroll
  for (int i = ty; i < 32; i += 8)
    Wt[(size_t)(bn + i) * K + bk + tx] = f2bf(tile[tx][i]);
}

__global__ void concat_bias(const float* __restrict__ b0, const float* __restrict__ b1,
                            const float* __restrict__ b2, const float* __restrict__ b3,
                            const float* __restrict__ b4, float* __restrict__ out)
{
  const int i = blockIdx.x * 256 + threadIdx.x;   // 5120 total
  const float* src;
  switch (i >> 10) {
    case 0: src = b0; break;
    case 1: src = b1; break;
    case 2: src = b2; break;
    case 3: src = b3; break;
    default: src = b4; break;
  }
  out[i] = src[i & 1023];
}

// ---------------------------------------------------------------------------
extern "C" void kernel_launch(void* const* d_in, const int* in_sizes, int n_in,
                              void* d_out, int out_size, void* d_ws, size_t ws_size,
                              hipStream_t stream)
{
  const float* x    = (const float*)d_in[0];
  const float* WQ1w = (const float*)d_in[1];  const float* WQ1b = (const float*)d_in[2];
  const float* WK1w = (const float*)d_in[3];  const float* WK1b = (const float*)d_in[4];
  const float* WQ2w = (const float*)d_in[5];  const float* WQ2b = (const float*)d_in[6];
  const float* WK2w = (const float*)d_in[7];  const float* WK2b = (const float*)d_in[8];
  const float* WVw  = (const float*)d_in[9];  const float* WVb  = (const float*)d_in[10];
  const float* WOw  = (const float*)d_in[11]; const float* WOb  = (const float*)d_in[12];
  const float* L1w  = (const float*)d_in[13]; const float* L1b  = (const float*)d_in[14];
  const float* L2w  = (const float*)d_in[15]; const float* L2b  = (const float*)d_in[16];

  char* ws = (char*)d_ws;
  size_t off = 0;
  unsigned short* x_bf = (unsigned short*)(ws + off); off += (size_t)33554432 * 2;   // [32768,1024]
  unsigned short* qw   = (unsigned short*)(ws + off); off += (size_t)5242880 * 2;    // [5120,1024]
  unsigned short* wot  = (unsigned short*)(ws + off); off += (size_t)1048576 * 2;    // [1024,1024]
  unsigned short* l1t  = (unsigned short*)(ws + off); off += (size_t)524288 * 2;     // [256,2048]
  float*          bcat = (float*)(ws + off);          off += (size_t)5120 * 4;
  unsigned short* qkv  = (unsigned short*)(ws + off); off += (size_t)32768 * 5120 * 2; // 320MB
  unsigned short* abuf = (unsigned short*)(ws + off); off += (size_t)33554432 * 2;
  unsigned short* hbuf = (unsigned short*)(ws + off); off += (size_t)16384 * 256 * 2;
  float*          lam  = (float*)(ws + off);          off += (size_t)16384 * 4;

  // conversions
  f32_to_bf16_k<<<4194304 / 256, 256, 0, stream>>>(x, x_bf, 4194304);
  dim3 tb(32, 8);
  const float* wsrc[5] = {WQ1w, WK1w, WQ2w, WK2w, WVw};
  for (int i = 0; i < 5; ++i)
    transpose_bf16_k<<<dim3(32, 32), tb, 0, stream>>>(wsrc[i], qw + (size_t)i * 1048576, 1024, 1024);
  transpose_bf16_k<<<dim3(32, 32), tb, 0, stream>>>(WOw, wot, 1024, 1024);
  transpose_bf16_k<<<dim3(8, 64), tb, 0, stream>>>(L1w, l1t, 2048, 256);
  concat_bias<<<20, 256, 0, stream>>>(WQ1b, WK1b, WQ2b, WK2b, WVb, bcat);

  // lambda net: h = relu(x @ L1 + b1)  [16384, 256]
  gemm_bf16_relu<<<dim3(128, 2), 256, 0, stream>>>(x_bf, l1t, L1b, hbuf, 2048, 256);
  lam_kernel<<<4096, 256, 0, stream>>>(hbuf, L2w, L2b, lam);

  // fused projections: [32768,1024] @ [1024,5120] -> qkv  (Q1|K1|Q2|K2|V)
  gemm256<0><<<dim3(128 * 20), 512, 0, stream>>>(x_bf, qw, bcat, qkv, nullptr, 1024, 5120, 20);

  // attention core
  attn_kernel<<<16384, 256, 0, stream>>>(qkv, lam, abuf);

  // output: attn @ WO + bias + residual(x), f32
  gemm256<2><<<dim3(128 * 4), 512, 0, stream>>>(abuf, wot, WOb, d_out, x, 1024, 1024, 4);
}

// Round 4
// 615.684 us; speedup vs baseline: 1.2244x; 1.0393x over previous
//
#include <hip/hip_runtime.h>
#include <stdint.h>

// ---------------------------------------------------------------------------
// AdaptiveDiffAttention on MI355X (gfx950)
// B=16384, DIM=2048, SD=1024, H=4, HD=256, LH=256
// Round 4: minimal-fence 4-phase K-loop. One builtin s_barrier per phase (no
// memory clobber -> compiler may hoist next-phase ds_reads under MFMA), one
// clobbered vmcnt(4) per tile (ph3). Stage placement & in-flight ledger:
//   ph0: AK1(t+1)->nbuf  ph1: BK1(t+1)->nbuf  ph2: AK0(t+2)->buf  ph3: BK0(t+2)->buf
//   steady in-flight 12; vmcnt(4) retires K1(t+1),K0(t+1), leaves K0(t+2).
// ---------------------------------------------------------------------------

#define BATCH  16384
#define ATT_SCALE 0.0625f // 256^-0.5

typedef __attribute__((ext_vector_type(8))) short   s16x8;
typedef __attribute__((ext_vector_type(4))) float   f32x4;
typedef __attribute__((ext_vector_type(8))) unsigned short u16x8;
typedef __attribute__((ext_vector_type(4))) unsigned short u16x4;

__device__ __forceinline__ unsigned short f2bf(float f) {
  unsigned u = __float_as_uint(f);
  u += 0x7FFFu + ((u >> 16) & 1u);   // RNE
  return (unsigned short)(u >> 16);
}
__device__ __forceinline__ float bf2f(unsigned short s) {
  return __uint_as_float((unsigned)s << 16);
}

__device__ __forceinline__ void async16(const void* g, void* l) {
  __builtin_amdgcn_global_load_lds((__attribute__((address_space(1))) void*)g,
                                   (__attribute__((address_space(3))) void*)l,
                                   16, 0, 0);
}

#define MFMA16(ACCBASE)                                                        \
  __builtin_amdgcn_s_setprio(1);                                               \
  _Pragma("unroll")                                                            \
  for (int mf = 0; mf < 4; ++mf) {                                             \
    _Pragma("unroll")                                                          \
    for (int nf = 0; nf < 4; ++nf)                                             \
      acc[(ACCBASE) + mf][nf] = __builtin_amdgcn_mfma_f32_16x16x32_bf16(       \
          aR[mf], bR[nf], acc[(ACCBASE) + mf][nf], 0, 0, 0);                   \
  }                                                                            \
  __builtin_amdgcn_s_setprio(0);

// ---------------------------------------------------------------------------
// 256x256 GEMM: C[M,N] = A[M,K](bf16) @ Bt[N,K]^T(bf16) + bias
// MODE 0: store bf16   MODE 2: +res(bf16), store f32
// 512 threads = 8 waves (2M x 4N), per-wave 128x64 output, BK=64.
// LDS: 2 buffers x {AK0,AK1,BK0,BK1} 16KB regions = 128KB.
// ---------------------------------------------------------------------------
template<int MODE>
__global__ __launch_bounds__(512, 2)
void gemm256(const unsigned short* __restrict__ A,
             const unsigned short* __restrict__ Bt,
             const float* __restrict__ bias,
             void* __restrict__ Cout,
             const unsigned short* __restrict__ res,
             int Kdim, int Ndim, int NN)
{
  __shared__ __align__(16) char lds[131072];
  const int tid  = threadIdx.x;
  const int lane = tid & 63, w = tid >> 6;
  const int wm = w >> 2, wn = w & 3;
  const int li = lane & 15, lc = lane >> 4;

  // T1: bijective XCD swizzle (m204), n-fast decode
  const int nwg = gridDim.x;
  const int q8 = nwg >> 3, r8 = nwg & 7;
  const int xcd = blockIdx.x & 7, pos = blockIdx.x >> 3;
  const int swz = (xcd < r8 ? xcd * (q8 + 1) : r8 * (q8 + 1) + (xcd - r8) * q8) + pos;
  const int bm = (swz / NN) * 256;
  const int bn = (swz % NN) * 256;

  // Staging geometry: half-K region = 16KB = [256 rows][32 elems]; thread does
  // 2x16B (rows r0, r0+16). Chunk-XOR swizzle c^=(r>>1)&3 (rule #21: linear
  // LDS dest + inverse-swizzled global source).
  const int r0  = w * 32 + (lane >> 2);
  const int csw = ((lane & 3) ^ ((r0 >> 1) & 3)) * 8;
  const size_t aS0 = (size_t)(bm + r0) * Kdim + csw;
  const size_t aS1 = (size_t)(bm + r0 + 16) * Kdim + csw;
  const size_t bS0 = (size_t)(bn + r0) * Kdim + csw;
  const size_t bS1 = (size_t)(bn + r0 + 16) * Kdim + csw;
  const int dL0 = w * 2048, dL1 = dL0 + 1024;

  // fragment read offsets (same swizzle on read side)
  const int fsw   = (lc ^ ((li >> 1) & 3)) << 4;
  const int afoff = (wm * 128 + li) * 64 + fsw;
  const int bfoff = 32768 + (wn * 64 + li) * 64 + fsw;

  f32x4 acc[8][4];
#pragma unroll
  for (int m = 0; m < 8; ++m)
#pragma unroll
    for (int n = 0; n < 4; ++n) acc[m][n] = (f32x4)0.f;

  const int NT = Kdim >> 6;

  // prologue: K0(0), K1(0), K0(1) = 12 loads; vmcnt(4) leaves {K0(1)}
  async16(A  + aS0,       lds + dL0);          async16(A  + aS1,       lds + dL1);
  async16(Bt + bS0,       lds + 32768 + dL0);  async16(Bt + bS1,       lds + 32768 + dL1);
  async16(A  + aS0 + 32,  lds + 16384 + dL0);  async16(A  + aS1 + 32,  lds + 16384 + dL1);
  async16(Bt + bS0 + 32,  lds + 49152 + dL0);  async16(Bt + bS1 + 32,  lds + 49152 + dL1);
  async16(A  + aS0 + 64,  lds + 65536 + dL0);  async16(A  + aS1 + 64,  lds + 65536 + dL1);
  async16(Bt + bS0 + 64,  lds + 98304 + dL0);  async16(Bt + bS1 + 64,  lds + 98304 + dL1);
  asm volatile("s_waitcnt vmcnt(4)" ::: "memory");
  __builtin_amdgcn_s_barrier();

  for (int t = 0; t < NT; ++t) {
    char* buf  = lds + (t & 1) * 65536;
    char* nbuf = lds + ((t + 1) & 1) * 65536;
    const size_t kA = (size_t)t * 64;
    const bool s1 = (t + 1 < NT), s2 = (t + 2 < NT);
    s16x8 aR[4], bR[4];

    // ---- phase 0: K0 m0-3 (8 rd); stage AK1(t+1) -> nbuf
    {
      const char* ab = buf + afoff;
      const char* bb = buf + bfoff;
#pragma unroll
      for (int i = 0; i < 4; ++i) aR[i] = *(const s16x8*)(ab + i * 1024);
#pragma unroll
      for (int i = 0; i < 4; ++i) bR[i] = *(const s16x8*)(bb + i * 1024);
      if (s1) {
        async16(A + aS0 + kA + 96, nbuf + 16384 + dL0);
        async16(A + aS1 + kA + 96, nbuf + 16384 + dL1);
      }
      MFMA16(0)
      __builtin_amdgcn_s_barrier();
    }
    // ---- phase 1: K0 m4-7 (4 rd); stage BK1(t+1) -> nbuf
    {
      const char* ab = buf + afoff + 4096;
#pragma unroll
      for (int i = 0; i < 4; ++i) aR[i] = *(const s16x8*)(ab + i * 1024);
      if (s1) {
        async16(Bt + bS0 + kA + 96, nbuf + 49152 + dL0);
        async16(Bt + bS1 + kA + 96, nbuf + 49152 + dL1);
      }
      MFMA16(4)
      __builtin_amdgcn_s_barrier();
    }
    // ---- phase 2: K1 m0-3 (8 rd); stage AK0(t+2) -> buf
    {
      const char* ab = buf + 16384 + afoff;
      const char* bb = buf + 16384 + bfoff;
#pragma unroll
      for (int i = 0; i < 4; ++i) aR[i] = *(const s16x8*)(ab + i * 1024);
#pragma unroll
      for (int i = 0; i < 4; ++i) bR[i] = *(const s16x8*)(bb + i * 1024);
      if (s2) {
        async16(A + aS0 + kA + 128, buf + dL0);
        async16(A + aS1 + kA + 128, buf + dL1);
      }
      MFMA16(0)
      __builtin_amdgcn_s_barrier();
    }
    // ---- phase 3: K1 m4-7 (4 rd); stage BK0(t+2) -> buf; counted wait
    {
      const char* ab = buf + 16384 + afoff + 4096;
#pragma unroll
      for (int i = 0; i < 4; ++i) aR[i] = *(const s16x8*)(ab + i * 1024);
      if (s2) {
        async16(Bt + bS0 + kA + 128, buf + 32768 + dL0);
        async16(Bt + bS1 + kA + 128, buf + 32768 + dL1);
      }
      MFMA16(4)
      if (t < NT - 2)       { asm volatile("s_waitcnt vmcnt(4)" ::: "memory"); }
      else if (t == NT - 2) { asm volatile("s_waitcnt vmcnt(0)" ::: "memory"); }
      __builtin_amdgcn_s_barrier();
    }
  }

  // ---- epilogue: per-wave private LDS region (12KB), coalesced stores ----
  float bv[4];
#pragma unroll
  for (int n = 0; n < 4; ++n) bv[n] = bias[bn + wn * 64 + n * 16 + li];

  if (MODE == 0) {
    unsigned short* Cb = (unsigned short*)Cout;
    unsigned short* wl0 = (unsigned short*)(lds + w * 12288);
#pragma unroll
    for (int mp = 0; mp < 4; ++mp) {
      unsigned short* wl = wl0 + (mp & 1) * 2304;
#pragma unroll
      for (int mi = 0; mi < 2; ++mi)
#pragma unroll
        for (int n = 0; n < 4; ++n)
#pragma unroll
          for (int jj = 0; jj < 4; ++jj) {
            float v = acc[mp * 2 + mi][n][jj] + bv[n];
            wl[(mi * 16 + lc * 4 + jj) * 72 + li + n * 16] = f2bf(v);
          }
#pragma unroll
      for (int i = 0; i < 4; ++i) {
        const int rr = i * 8 + (lane >> 3);
        u16x8 vv = *(const u16x8*)(wl + rr * 72 + (lane & 7) * 8);
        const size_t gi = (size_t)(bm + wm * 128 + mp * 32 + rr) * Ndim
                        + bn + wn * 64 + (lane & 7) * 8;
        *(u16x8*)(Cb + gi) = vv;
      }
    }
  } else {
    float* Cf = (float*)Cout;
    float* wl0 = (float*)(lds + w * 12288);
#pragma unroll
    for (int m = 0; m < 8; ++m) {
      float* wl = wl0 + (m & 1) * 1088;
#pragma unroll
      for (int n = 0; n < 4; ++n)
#pragma unroll
        for (int jj = 0; jj < 4; ++jj)
          wl[(lc * 4 + jj) * 68 + li + n * 16] = acc[m][n][jj] + bv[n];
#pragma unroll
      for (int i = 0; i < 4; ++i) {
        const int rr = i * 4 + lc;
        f32x4 vv = *(const f32x4*)(wl + rr * 68 + li * 4);
        const size_t gi = (size_t)(bm + wm * 128 + m * 16 + rr) * Ndim
                        + bn + wn * 64 + li * 4;
        const u16x4 rv = *(const u16x4*)(res + gi);
        f32x4 ov;
#pragma unroll
        for (int jj = 0; jj < 4; ++jj) ov[jj] = vv[jj] + bf2f(rv[jj]);
        *(f32x4*)(Cf + gi) = ov;
      }
    }
  }
}

// ---------------------------------------------------------------------------
// 128x128 GEMM (round-1 structure) — lambda-net hidden GEMM only.
// ---------------------------------------------------------------------------
__global__ __launch_bounds__(256, 2)
void gemm_bf16_relu(const unsigned short* __restrict__ A,
                    const unsigned short* __restrict__ Bt,
                    const float* __restrict__ bias,
                    unsigned short* __restrict__ Cout,
                    int Kdim, int Ndim)
{
  __shared__ __align__(16) unsigned short lA[128 * 32];
  __shared__ __align__(16) unsigned short lB[128 * 32];
  const int tid  = threadIdx.x;
  const int lane = tid & 63, wid = tid >> 6;
  const int wm = wid >> 1, wn = wid & 1;
  const int bm = blockIdx.x * 128, bn = blockIdx.y * 128;

  f32x4 acc[4][4];
#pragma unroll
  for (int i = 0; i < 4; ++i)
#pragma unroll
    for (int j = 0; j < 4; ++j) acc[i][j] = (f32x4)0.f;

  const int ar = tid >> 2;
  const int ac = (tid & 3) * 8;
  const unsigned short* aG0 = A  + (size_t)(bm + ar) * Kdim + ac;
  const unsigned short* aG1 = aG0 + (size_t)64 * Kdim;
  const unsigned short* bG0 = Bt + (size_t)(bn + ar) * Kdim + ac;
  const unsigned short* bG1 = bG0 + (size_t)64 * Kdim;
  unsigned short* aL0 = lA + wid * 512;
  unsigned short* aL1 = lA + 2048 + wid * 512;
  unsigned short* bL0 = lB + wid * 512;
  unsigned short* bL1 = lB + 2048 + wid * 512;

  const unsigned short* aF = lA + (wm * 64 + (lane & 15)) * 32 + (lane >> 4) * 8;
  const unsigned short* bF = lB + (wn * 64 + (lane & 15)) * 32 + (lane >> 4) * 8;

  for (int k0 = 0; k0 < Kdim; k0 += 32) {
    async16(aG0, aL0); async16(aG1, aL1);
    async16(bG0, bL0); async16(bG1, bL1);
    aG0 += 32; aG1 += 32; bG0 += 32; bG1 += 32;
    __syncthreads();
    s16x8 af[4], bw[4];
#pragma unroll
    for (int m = 0; m < 4; ++m) af[m] = *(const s16x8*)(aF + m * 512);
#pragma unroll
    for (int n = 0; n < 4; ++n) bw[n] = *(const s16x8*)(bF + n * 512);
#pragma unroll
    for (int m = 0; m < 4; ++m)
#pragma unroll
      for (int n = 0; n < 4; ++n)
        acc[m][n] = __builtin_amdgcn_mfma_f32_16x16x32_bf16(af[m], bw[n], acc[m][n], 0, 0, 0);
    __syncthreads();
  }

  const int r0 = bm + wm * 64 + ((lane >> 4) << 2);
  const int c0 = bn + wn * 64 + (lane & 15);
#pragma unroll
  for (int m = 0; m < 4; ++m)
#pragma unroll
    for (int n = 0; n < 4; ++n) {
      const int col = c0 + n * 16;
      const float bvv = bias[col];
#pragma unroll
      for (int j = 0; j < 4; ++j) {
        const int row = r0 + m * 16 + j;
        Cout[(size_t)row * Ndim + col] = f2bf(fmaxf(acc[m][n][j] + bvv, 0.f));
      }
    }
}

// ---------------------------------------------------------------------------
// lam[row] = sigmoid( relu_h[row,:] . L2w + L2b ) ; one wave per row
// ---------------------------------------------------------------------------
__global__ void lam_kernel(const unsigned short* __restrict__ h,
                           const float* __restrict__ L2w,
                           const float* __restrict__ L2b,
                           float* __restrict__ lam)
{
  const int lane = threadIdx.x & 63, wid = threadIdx.x >> 6;
  const int row = blockIdx.x * 4 + wid;
  const u16x4 hv = *(const u16x4*)(h + (size_t)row * 256 + lane * 4);
  const float4 wv = ((const float4*)L2w)[lane];
  float s = bf2f(hv[0]) * wv.x + bf2f(hv[1]) * wv.y +
            bf2f(hv[2]) * wv.z + bf2f(hv[3]) * wv.w;
#pragma unroll
  for (int m = 32; m >= 1; m >>= 1) s += __shfl_xor(s, m, 64);
  if (lane == 0) lam[row] = 1.f / (1.f + expf(-(s + L2b[0])));
}

// ---------------------------------------------------------------------------
// Attention core. qkv = [32768, 5120] bf16 (Q1|K1|Q2|K2|V per row).
// One block per batch, one wave per head; lanes 0-31 token 0, 32-63 token 1.
// ---------------------------------------------------------------------------
__global__ __launch_bounds__(256)
void attn_kernel(const unsigned short* __restrict__ qkv,
                 const float* __restrict__ lam,
                 unsigned short* __restrict__ aout)
{
  const int b = blockIdx.x;
  const int hd = threadIdx.x >> 6;
  const int lane = threadIdx.x & 63;
  const int g = lane >> 5;          // token index
  const int l5 = lane & 31;
  const size_t base = (size_t)(2 * b + g) * 5120 + hd * 256 + l5 * 8;

  const u16x8 q1v = *(const u16x8*)(qkv + base);
  const u16x8 k1v = *(const u16x8*)(qkv + base + 1024);
  const u16x8 q2v = *(const u16x8*)(qkv + base + 2048);
  const u16x8 k2v = *(const u16x8*)(qkv + base + 3072);
  const u16x8 vvv = *(const u16x8*)(qkv + base + 4096);

  float q1[8], k1[8], q2[8], k2[8], vf[8];
#pragma unroll
  for (int j = 0; j < 8; ++j) {
    q1[j] = bf2f(q1v[j]); k1[j] = bf2f(k1v[j]);
    q2[j] = bf2f(q2v[j]); k2[j] = bf2f(k2v[j]);
    vf[j] = bf2f(vvv[j]);
  }

  float ss1 = 0.f, sc1 = 0.f, ss2 = 0.f, sc2 = 0.f;
#pragma unroll
  for (int j = 0; j < 8; ++j) {
    const float k1o = __shfl_xor(k1[j], 32, 64);
    const float k2o = __shfl_xor(k2[j], 32, 64);
    ss1 += q1[j] * k1[j]; sc1 += q1[j] * k1o;
    ss2 += q2[j] * k2[j]; sc2 += q2[j] * k2o;
  }
#pragma unroll
  for (int m = 16; m >= 1; m >>= 1) {
    ss1 += __shfl_xor(ss1, m, 64); sc1 += __shfl_xor(sc1, m, 64);
    ss2 += __shfl_xor(ss2, m, 64); sc2 += __shfl_xor(sc2, m, 64);
  }

  float e0 = ss1 * ATT_SCALE, e1 = sc1 * ATT_SCALE;
  float mx = fmaxf(e0, e1);
  float xs = expf(e0 - mx), xc = expf(e1 - mx);
  float inv = 1.f / (xs + xc);
  const float a1s = xs * inv, a1c = xc * inv;

  e0 = ss2 * ATT_SCALE; e1 = sc2 * ATT_SCALE;
  mx = fmaxf(e0, e1);
  xs = expf(e0 - mx); xc = expf(e1 - mx);
  inv = 1.f / (xs + xc);
  const float a2s = xs * inv, a2c = xc * inv;

  const float lm = lam[b];
  const float ps = fmaxf(a1s - lm * a2s, 0.f);
  const float pc = fmaxf(a1c - lm * a2c, 0.f);

  u16x8 o;
#pragma unroll
  for (int j = 0; j < 8; ++j) {
    const float vo = __shfl_xor(vf[j], 32, 64);
    o[j] = f2bf(ps * vf[j] + pc * vo);
  }
  *(u16x8*)(aout + (size_t)(2 * b + g) * 1024 + hd * 256 + l5 * 8) = o;
}

// ---------------------------------------------------------------------------
// conversions
// ---------------------------------------------------------------------------
__global__ void f32_to_bf16_k(const float* __restrict__ in,
                              unsigned short* __restrict__ out, int n8)
{
  const int i = blockIdx.x * 256 + threadIdx.x;
  if (i >= n8) return;
  const float4* p = (const float4*)in + (size_t)i * 2;
  float4 a = p[0], b = p[1];
  u16x8 v;
  v[0] = f2bf(a.x); v[1] = f2bf(a.y); v[2] = f2bf(a.z); v[3] = f2bf(a.w);
  v[4] = f2bf(b.x); v[5] = f2bf(b.y); v[6] = f2bf(b.z); v[7] = f2bf(b.w);
  *(u16x8*)(out + (size_t)i * 8) = v;
}

// W f32 [K,N] -> Wt bf16 [N,K]; grid (N/32, K/32), block (32,8)
__global__ void transpose_bf16_k(const float* __restrict__ W,
                                 unsigned short* __restrict__ Wt, int K, int N)
{
  __shared__ float tile[32][33];
  const int bn = blockIdx.x * 32, bk = blockIdx.y * 32;
  const int tx = threadIdx.x, ty = threadIdx.y;
#pragma unroll
  for (int i = ty; i < 32; i += 8)
    tile[i][tx] = W[(size_t)(bk + i) * N + bn + tx];
  __syncthreads();
#pragma unroll
  for (int i = ty; i < 32; i += 8)
    Wt[(size_t)(bn + i) * K + bk + tx] = f2bf(tile[tx][i]);
}

__global__ void concat_bias(const float* __restrict__ b0, const float* __restrict__ b1,
                            const float* __restrict__ b2, const float* __restrict__ b3,
                            const float* __restrict__ b4, float* __restrict__ out)
{
  const int i = blockIdx.x * 256 + threadIdx.x;   // 5120 total
  const float* src;
  switch (i >> 10) {
    case 0: src = b0; break;
    case 1: src = b1; break;
    case 2: src = b2; break;
    case 3: src = b3; break;
    default: src = b4; break;
  }
  out[i] = src[i & 1023];
}

// ---------------------------------------------------------------------------
extern "C" void kernel_launch(void* const* d_in, const int* in_sizes, int n_in,
                              void* d_out, int out_size, void* d_ws, size_t ws_size,
                              hipStream_t stream)
{
  const float* x    = (const float*)d_in[0];
  const float* WQ1w = (const float*)d_in[1];  const float* WQ1b = (const float*)d_in[2];
  const float* WK1w = (const float*)d_in[3];  const float* WK1b = (const float*)d_in[4];
  const float* WQ2w = (const float*)d_in[5];  const float* WQ2b = (const float*)d_in[6];
  const float* WK2w = (const float*)d_in[7];  const float* WK2b = (const float*)d_in[8];
  const float* WVw  = (const float*)d_in[9];  const float* WVb  = (const float*)d_in[10];
  const float* WOw  = (const float*)d_in[11]; const float* WOb  = (const float*)d_in[12];
  const float* L1w  = (const float*)d_in[13]; const float* L1b  = (const float*)d_in[14];
  const float* L2w  = (const float*)d_in[15]; const float* L2b  = (const float*)d_in[16];

  char* ws = (char*)d_ws;
  size_t off = 0;
  unsigned short* x_bf = (unsigned short*)(ws + off); off += (size_t)33554432 * 2;   // [32768,1024]
  unsigned short* qw   = (unsigned short*)(ws + off); off += (size_t)5242880 * 2;    // [5120,1024]
  unsigned short* wot  = (unsigned short*)(ws + off); off += (size_t)1048576 * 2;    // [1024,1024]
  unsigned short* l1t  = (unsigned short*)(ws + off); off += (size_t)524288 * 2;     // [256,2048]
  float*          bcat = (float*)(ws + off);          off += (size_t)5120 * 4;
  unsigned short* qkv  = (unsigned short*)(ws + off); off += (size_t)32768 * 5120 * 2; // 320MB
  unsigned short* abuf = (unsigned short*)(ws + off); off += (size_t)33554432 * 2;
  unsigned short* hbuf = (unsigned short*)(ws + off); off += (size_t)16384 * 256 * 2;
  float*          lam  = (float*)(ws + off);          off += (size_t)16384 * 4;

  // conversions
  f32_to_bf16_k<<<4194304 / 256, 256, 0, stream>>>(x, x_bf, 4194304);
  dim3 tb(32, 8);
  const float* wsrc[5] = {WQ1w, WK1w, WQ2w, WK2w, WVw};
  for (int i = 0; i < 5; ++i)
    transpose_bf16_k<<<dim3(32, 32), tb, 0, stream>>>(wsrc[i], qw + (size_t)i * 1048576, 1024, 1024);
  transpose_bf16_k<<<dim3(32, 32), tb, 0, stream>>>(WOw, wot, 1024, 1024);
  transpose_bf16_k<<<dim3(8, 64), tb, 0, stream>>>(L1w, l1t, 2048, 256);
  concat_bias<<<20, 256, 0, stream>>>(WQ1b, WK1b, WQ2b, WK2b, WVb, bcat);

  // lambda net: h = relu(x @ L1 + b1)  [16384, 256]
  gemm_bf16_relu<<<dim3(128, 2), 256, 0, stream>>>(x_bf, l1t, L1b, hbuf, 2048, 256);
  lam_kernel<<<4096, 256, 0, stream>>>(hbuf, L2w, L2b, lam);

  // fused projections: [32768,1024] @ [1024,5120] -> qkv  (Q1|K1|Q2|K2|V)
  gemm256<0><<<dim3(128 * 20), 512, 0, stream>>>(x_bf, qw, bcat, qkv, nullptr, 1024, 5120, 20);

  // attention core
  attn_kernel<<<16384, 256, 0, stream>>>(qkv, lam, abuf);

  // output: attn @ WO + bias + residual(x_bf), f32
  gemm256<2><<<dim3(128 * 4), 512, 0, stream>>>(abuf, wot, WOb, d_out, x_bf, 1024, 1024, 4);
}